// Round 2
// baseline (3957.512 us; speedup 1.0000x reference)
//
#include <hip/hip_runtime.h>
#include <math.h>

#define N_NODES  10000
#define N_EDGES  160000
#define HID      128
#define N_LAYERS 6
#define N_RBF    50
#define EDGE_IN  307     // 2*HID + 1 + N_RBF
#define KPAD     320     // EDGE_IN padded to multiple of 16

__device__ __forceinline__ float silu_f(float x) {
    return x / (1.0f + __expf(-x));
}

// ---------------- setup kernels ----------------

__global__ void init_feats_kernel(const int* __restrict__ an,
                                  const float* __restrict__ embed,
                                  float* __restrict__ feats) {
    int idx = blockIdx.x * blockDim.x + threadIdx.x;
    if (idx < N_NODES * HID) {
        int i = idx >> 7, j = idx & 127;
        feats[idx] = embed[an[i] * HID + j];
    }
}

__global__ void hist_kernel(const int* __restrict__ row, int* __restrict__ cnt) {
    int e = blockIdx.x * blockDim.x + threadIdx.x;
    if (e < N_EDGES) atomicAdd(&cnt[row[e]], 1);
}

__global__ void scan_kernel(const int* __restrict__ cnt, int* __restrict__ cursor) {
    __shared__ int buf[256];
    __shared__ int carry;
    int tid = threadIdx.x;
    if (tid == 0) carry = 0;
    __syncthreads();
    for (int base = 0; base < N_NODES; base += 256) {
        int v = (base + tid < N_NODES) ? cnt[base + tid] : 0;
        buf[tid] = v;
        __syncthreads();
        for (int off = 1; off < 256; off <<= 1) {
            int x = (tid >= off) ? buf[tid - off] : 0;
            __syncthreads();
            buf[tid] += x;
            __syncthreads();
        }
        int excl = buf[tid] - v + carry;
        if (base + tid < N_NODES) cursor[base + tid] = excl;
        int tot = buf[255];
        __syncthreads();
        if (tid == 0) carry += tot;
        __syncthreads();
    }
}

__global__ void scatter_kernel(const int* __restrict__ row, int* __restrict__ cursor,
                               int* __restrict__ sorted) {
    int e = blockIdx.x * blockDim.x + threadIdx.x;
    if (e < N_EDGES) {
        int p = atomicAdd(&cursor[row[e]], 1);
        sorted[p] = e;
    }
}

// per-edge geometry from ORIGINAL coords, stored in SORTED edge order:
// d0 = |coords[row]-coords[col]|, cut0 = 0.5*(cos(pi*d/10)+1)*(d<10)
__global__ void edgegeom_kernel(const int* __restrict__ sorted,
                                const int* __restrict__ erow, const int* __restrict__ ecol,
                                const float* __restrict__ coords,
                                float* __restrict__ d0, float* __restrict__ cut0) {
    int p = blockIdx.x * 256 + threadIdx.x;
    if (p < N_EDGES) {
        int e = sorted[p];
        int r = erow[e], c = ecol[e];
        float dx = coords[3*r]   - coords[3*c];
        float dy = coords[3*r+1] - coords[3*c+1];
        float dz = coords[3*r+2] - coords[3*c+2];
        float d = sqrtf(dx*dx + dy*dy + dz*dz);
        d0[p] = d;
        cut0[p] = (d < 10.0f) ? 0.5f * (__cosf(0.31415926535f * d) + 1.0f) : 0.0f;
    }
}

// ---------------- fused per-layer edge kernel ----------------
// tile: 64 (sorted) edges x 128 cols, 256 threads, acc 4x8 per thread

#define FMA8(r, aq) \
    acc[r][0] += (aq)*b0.x; acc[r][1] += (aq)*b0.y; acc[r][2] += (aq)*b0.z; acc[r][3] += (aq)*b0.w; \
    acc[r][4] += (aq)*b1.x; acc[r][5] += (aq)*b1.y; acc[r][6] += (aq)*b1.z; acc[r][7] += (aq)*b1.w;

__global__ __launch_bounds__(256) void edge_kernel(
    const int* __restrict__ sorted,
    const int* __restrict__ erow, const int* __restrict__ ecol,
    const float* __restrict__ coords, float* __restrict__ coords_next,
    const float* __restrict__ feats,
    const float* __restrict__ d0g, const float* __restrict__ cut0g,
    const float* __restrict__ mw1, const float* __restrict__ mb1,
    const float* __restrict__ mw2, const float* __restrict__ mb2,
    const float* __restrict__ cw1, const float* __restrict__ cb1,
    const float* __restrict__ cw2, const float* __restrict__ cb2,
    float* __restrict__ agg)
{
    __shared__ float sA[64][20];        // staged ef K-tile (stride 20: <=2-way, free)
    __shared__ float sB[16][HID];       // staged weight K-tile
    __shared__ float sH[64][HID + 4];   // h1 -> m -> c1 (stride 132: <=2-way, free)
    __shared__ int   srow[64];
    __shared__ int   scol[64];
    __shared__ float sdiff[64][3];
    __shared__ float sdist[64];
    __shared__ float sd0[64], scut[64];
    __shared__ float sW[64];
    __shared__ float sV[HID];

    int tid = threadIdx.x;
    int p0 = blockIdx.x * 64;

    if (tid < 64) {
        int e = sorted[p0 + tid];
        int r = erow[e], c = ecol[e];
        srow[tid] = r; scol[tid] = c;
        float dx = coords[3*r]   - coords[3*c];
        float dy = coords[3*r+1] - coords[3*c+1];
        float dz = coords[3*r+2] - coords[3*c+2];
        sdiff[tid][0] = dx; sdiff[tid][1] = dy; sdiff[tid][2] = dz;
        sdist[tid] = dx*dx + dy*dy + dz*dz;
        sd0[tid]  = d0g[p0 + tid];
        scut[tid] = cut0g[p0 + tid];
    }
    if (tid < HID) sV[tid] = cw2[tid];
    __syncthreads();

    const int tr = tid >> 4, tc = tid & 15;
    const int r0 = tr * 4, c0 = tc * 4, c1 = c0 + 64;
    const int el = tid >> 2, kq = (tid & 3) * 4;

    float acc[4][8];
    #pragma unroll
    for (int i = 0; i < 4; i++)
        #pragma unroll
        for (int j = 0; j < 8; j++) acc[i][j] = 0.f;

    // ---- phase 1: h1 = silu(ef @ mw1 + mb1), K = 320 (307 padded) ----
    for (int kt = 0; kt < KPAD / 16; ++kt) {
        int k0 = kt * 16;
        {   // stage A: ef[64][16]
            int k = k0 + kq;
            if (k < 2 * HID) {
                int node = (k < HID) ? srow[el] : scol[el];
                float4 v = *(const float4*)&feats[(size_t)node * HID + (k & (HID - 1))];
                *(float4*)&sA[el][kq] = v;
            } else {
                float dv = sd0[el], ct = scut[el];
                #pragma unroll
                for (int j = 0; j < 4; j++) {
                    int k2 = k + j;
                    float v = 0.f;
                    if (k2 == 2 * HID) v = sdist[el];
                    else if (k2 > 2 * HID && k2 < EDGE_IN) {
                        float cen = (float)(k2 - (2 * HID + 1)) * (10.0f / 49.0f);
                        float t = dv - cen;
                        v = __expf(-t * t * 5.0f) * ct;   // width = 0.2 -> *5
                    }
                    sA[el][kq + j] = v;
                }
            }
        }
        {   // stage B: mw1 rows k0..k0+15
            int bk = tid >> 4, bj = (tid & 15) * 8;
            int k = k0 + bk;
            float4 v0 = make_float4(0,0,0,0), v1 = v0;
            if (k < EDGE_IN) {
                v0 = *(const float4*)&mw1[(size_t)k * HID + bj];
                v1 = *(const float4*)&mw1[(size_t)k * HID + bj + 4];
            }
            *(float4*)&sB[bk][bj]     = v0;
            *(float4*)&sB[bk][bj + 4] = v1;
        }
        __syncthreads();
        #pragma unroll
        for (int kk4 = 0; kk4 < 4; ++kk4) {
            float4 a0 = *(const float4*)&sA[r0 + 0][kk4 * 4];
            float4 a1 = *(const float4*)&sA[r0 + 1][kk4 * 4];
            float4 a2 = *(const float4*)&sA[r0 + 2][kk4 * 4];
            float4 a3 = *(const float4*)&sA[r0 + 3][kk4 * 4];
            #pragma unroll
            for (int q = 0; q < 4; ++q) {
                int kk = kk4 * 4 + q;
                float4 b0 = *(const float4*)&sB[kk][c0];
                float4 b1 = *(const float4*)&sB[kk][c1];
                float q0 = ((const float*)&a0)[q], q1 = ((const float*)&a1)[q];
                float q2 = ((const float*)&a2)[q], q3 = ((const float*)&a3)[q];
                FMA8(0, q0) FMA8(1, q1) FMA8(2, q2) FMA8(3, q3)
            }
        }
        __syncthreads();
    }
    #pragma unroll
    for (int i = 0; i < 4; i++) {
        float4 o0, o1;
        o0.x = silu_f(acc[i][0] + mb1[c0+0]); o0.y = silu_f(acc[i][1] + mb1[c0+1]);
        o0.z = silu_f(acc[i][2] + mb1[c0+2]); o0.w = silu_f(acc[i][3] + mb1[c0+3]);
        o1.x = silu_f(acc[i][4] + mb1[c1+0]); o1.y = silu_f(acc[i][5] + mb1[c1+1]);
        o1.z = silu_f(acc[i][6] + mb1[c1+2]); o1.w = silu_f(acc[i][7] + mb1[c1+3]);
        *(float4*)&sH[r0 + i][c0] = o0;
        *(float4*)&sH[r0 + i][c1] = o1;
    }
    __syncthreads();

    // ---- phase 2: m = silu(h1 @ mw2 + mb2), K = 128, A = sH ----
    #pragma unroll
    for (int i = 0; i < 4; i++)
        #pragma unroll
        for (int j = 0; j < 8; j++) acc[i][j] = 0.f;
    for (int kt = 0; kt < 8; ++kt) {
        int k0 = kt * 16;
        {
            int bk = tid >> 4, bj = (tid & 15) * 8;
            int k = k0 + bk;
            *(float4*)&sB[bk][bj]     = *(const float4*)&mw2[(size_t)k * HID + bj];
            *(float4*)&sB[bk][bj + 4] = *(const float4*)&mw2[(size_t)k * HID + bj + 4];
        }
        __syncthreads();
        #pragma unroll
        for (int kk4 = 0; kk4 < 4; ++kk4) {
            float4 a0 = *(const float4*)&sH[r0 + 0][k0 + kk4 * 4];
            float4 a1 = *(const float4*)&sH[r0 + 1][k0 + kk4 * 4];
            float4 a2 = *(const float4*)&sH[r0 + 2][k0 + kk4 * 4];
            float4 a3 = *(const float4*)&sH[r0 + 3][k0 + kk4 * 4];
            #pragma unroll
            for (int q = 0; q < 4; ++q) {
                int kk = kk4 * 4 + q;
                float4 b0 = *(const float4*)&sB[kk][c0];
                float4 b1 = *(const float4*)&sB[kk][c1];
                float q0 = ((const float*)&a0)[q], q1 = ((const float*)&a1)[q];
                float q2 = ((const float*)&a2)[q], q3 = ((const float*)&a3)[q];
                FMA8(0, q0) FMA8(1, q1) FMA8(2, q2) FMA8(3, q3)
            }
        }
        __syncthreads();
    }
    #pragma unroll
    for (int i = 0; i < 4; i++) {
        float4 o0, o1;
        o0.x = silu_f(acc[i][0] + mb2[c0+0]); o0.y = silu_f(acc[i][1] + mb2[c0+1]);
        o0.z = silu_f(acc[i][2] + mb2[c0+2]); o0.w = silu_f(acc[i][3] + mb2[c0+3]);
        o1.x = silu_f(acc[i][4] + mb2[c1+0]); o1.y = silu_f(acc[i][5] + mb2[c1+1]);
        o1.z = silu_f(acc[i][6] + mb2[c1+2]); o1.w = silu_f(acc[i][7] + mb2[c1+3]);
        *(float4*)&sH[r0 + i][c0] = o0;   // sH now holds m
        *(float4*)&sH[r0 + i][c1] = o1;
    }
    __syncthreads();

    // ---- phase 3: c1t = silu(m @ cw1 + cb1), K = 128, A = sH(m) ----
    #pragma unroll
    for (int i = 0; i < 4; i++)
        #pragma unroll
        for (int j = 0; j < 8; j++) acc[i][j] = 0.f;
    for (int kt = 0; kt < 8; ++kt) {
        int k0 = kt * 16;
        {
            int bk = tid >> 4, bj = (tid & 15) * 8;
            int k = k0 + bk;
            *(float4*)&sB[bk][bj]     = *(const float4*)&cw1[(size_t)k * HID + bj];
            *(float4*)&sB[bk][bj + 4] = *(const float4*)&cw1[(size_t)k * HID + bj + 4];
        }
        __syncthreads();
        #pragma unroll
        for (int kk4 = 0; kk4 < 4; ++kk4) {
            float4 a0 = *(const float4*)&sH[r0 + 0][k0 + kk4 * 4];
            float4 a1 = *(const float4*)&sH[r0 + 1][k0 + kk4 * 4];
            float4 a2 = *(const float4*)&sH[r0 + 2][k0 + kk4 * 4];
            float4 a3 = *(const float4*)&sH[r0 + 3][k0 + kk4 * 4];
            #pragma unroll
            for (int q = 0; q < 4; ++q) {
                int kk = kk4 * 4 + q;
                float4 b0 = *(const float4*)&sB[kk][c0];
                float4 b1 = *(const float4*)&sB[kk][c1];
                float q0 = ((const float*)&a0)[q], q1 = ((const float*)&a1)[q];
                float q2 = ((const float*)&a2)[q], q3 = ((const float*)&a3)[q];
                FMA8(0, q0) FMA8(1, q1) FMA8(2, q2) FMA8(3, q3)
            }
        }
        __syncthreads();
    }

    // ---- agg scatter: run-reduce m (sH) over sorted rows ----
    // Each thread owns rows [tr*4, tr*4+4) and cols {c0..c0+3, c1..c1+3}:
    // every (node,col) contribution counted exactly once.
    {
        float g0[4] = {0,0,0,0}, g1[4] = {0,0,0,0};
        int rbeg = tr * 4;
        #pragma unroll
        for (int r = rbeg; r < rbeg + 4; ++r) {
            float4 v0 = *(const float4*)&sH[r][c0];
            float4 v1 = *(const float4*)&sH[r][c1];
            g0[0]+=v0.x; g0[1]+=v0.y; g0[2]+=v0.z; g0[3]+=v0.w;
            g1[0]+=v1.x; g1[1]+=v1.y; g1[2]+=v1.z; g1[3]+=v1.w;
            if (r == rbeg + 3 || srow[r + 1] != srow[r]) {
                float* dst = &agg[(size_t)srow[r] * HID];
                atomicAdd(&dst[c0+0], g0[0]); atomicAdd(&dst[c0+1], g0[1]);
                atomicAdd(&dst[c0+2], g0[2]); atomicAdd(&dst[c0+3], g0[3]);
                atomicAdd(&dst[c1+0], g1[0]); atomicAdd(&dst[c1+1], g1[1]);
                atomicAdd(&dst[c1+2], g1[2]); atomicAdd(&dst[c1+3], g1[3]);
                g0[0]=g0[1]=g0[2]=g0[3]=0.f; g1[0]=g1[1]=g1[2]=g1[3]=0.f;
            }
        }
    }
    __syncthreads();

    // write c1t into sH
    #pragma unroll
    for (int i = 0; i < 4; i++) {
        float4 o0, o1;
        o0.x = silu_f(acc[i][0] + cb1[c0+0]); o0.y = silu_f(acc[i][1] + cb1[c0+1]);
        o0.z = silu_f(acc[i][2] + cb1[c0+2]); o0.w = silu_f(acc[i][3] + cb1[c0+3]);
        o1.x = silu_f(acc[i][4] + cb1[c1+0]); o1.y = silu_f(acc[i][5] + cb1[c1+1]);
        o1.z = silu_f(acc[i][6] + cb1[c1+2]); o1.w = silu_f(acc[i][7] + cb1[c1+3]);
        *(float4*)&sH[r0 + i][c0] = o0;
        *(float4*)&sH[r0 + i][c1] = o1;
    }
    __syncthreads();

    // w = c1t @ cw2 + cb2
    if (tid < 64) {
        float s = cb2[0];
        for (int k = 0; k < HID; k++) s += sH[tid][k] * sV[k];
        sW[tid] = s;
    }
    __syncthreads();

    // coords update: per-row leader reduces its run, 3 atomics per distinct row
    if (tid < 64) {
        bool leader = (tid == 0) || (srow[tid] != srow[tid - 1]);
        if (leader) {
            int rr = srow[tid];
            float ax = 0.f, ay = 0.f, az = 0.f;
            for (int k = tid; k < 64 && srow[k] == rr; ++k) {
                ax += sW[k] * sdiff[k][0];
                ay += sW[k] * sdiff[k][1];
                az += sW[k] * sdiff[k][2];
            }
            atomicAdd(&coords_next[3*rr+0], ax);
            atomicAdd(&coords_next[3*rr+1], ay);
            atomicAdd(&coords_next[3*rr+2], az);
        }
    }
}

// ---------------- node feature update: feats' = silu([feats|agg] @ fw + fb) ----------------
__global__ __launch_bounds__(256) void node_kernel(
    const float* __restrict__ feats, const float* __restrict__ agg,
    const float* __restrict__ fw, const float* __restrict__ fb,
    float* __restrict__ out)
{
    __shared__ float sA[64][20];
    __shared__ float sB[16][HID];
    int tid = threadIdx.x;
    int n0 = blockIdx.x * 64;
    const int tr = tid >> 4, tc = tid & 15;
    const int r0 = tr * 4, c0 = tc * 4, c1 = c0 + 64;
    const int el = tid >> 2, kq = (tid & 3) * 4;

    float acc[4][8];
    #pragma unroll
    for (int i = 0; i < 4; i++)
        #pragma unroll
        for (int j = 0; j < 8; j++) acc[i][j] = 0.f;

    for (int kt = 0; kt < 16; ++kt) {   // K = 256
        int k0 = kt * 16;
        {
            int k = k0 + kq;
            int node = n0 + el;
            float4 v = make_float4(0,0,0,0);
            if (node < N_NODES) {
                const float* src = (k < HID) ? &feats[(size_t)node * HID + k]
                                             : &agg[(size_t)node * HID + (k - HID)];
                v = *(const float4*)src;
            }
            *(float4*)&sA[el][kq] = v;
        }
        {
            int bk = tid >> 4, bj = (tid & 15) * 8;
            int k = k0 + bk;
            *(float4*)&sB[bk][bj]     = *(const float4*)&fw[(size_t)k * HID + bj];
            *(float4*)&sB[bk][bj + 4] = *(const float4*)&fw[(size_t)k * HID + bj + 4];
        }
        __syncthreads();
        #pragma unroll
        for (int kk4 = 0; kk4 < 4; ++kk4) {
            float4 a0 = *(const float4*)&sA[r0 + 0][kk4 * 4];
            float4 a1 = *(const float4*)&sA[r0 + 1][kk4 * 4];
            float4 a2 = *(const float4*)&sA[r0 + 2][kk4 * 4];
            float4 a3 = *(const float4*)&sA[r0 + 3][kk4 * 4];
            #pragma unroll
            for (int q = 0; q < 4; ++q) {
                int kk = kk4 * 4 + q;
                float4 b0 = *(const float4*)&sB[kk][c0];
                float4 b1 = *(const float4*)&sB[kk][c1];
                float q0 = ((const float*)&a0)[q], q1 = ((const float*)&a1)[q];
                float q2 = ((const float*)&a2)[q], q3 = ((const float*)&a3)[q];
                FMA8(0, q0) FMA8(1, q1) FMA8(2, q2) FMA8(3, q3)
            }
        }
        __syncthreads();
    }
    #pragma unroll
    for (int i = 0; i < 4; i++) {
        int node = n0 + r0 + i;
        if (node < N_NODES) {
            float4 o0, o1;
            o0.x = silu_f(acc[i][0] + fb[c0+0]); o0.y = silu_f(acc[i][1] + fb[c0+1]);
            o0.z = silu_f(acc[i][2] + fb[c0+2]); o0.w = silu_f(acc[i][3] + fb[c0+3]);
            o1.x = silu_f(acc[i][4] + fb[c1+0]); o1.y = silu_f(acc[i][5] + fb[c1+1]);
            o1.z = silu_f(acc[i][6] + fb[c1+2]); o1.w = silu_f(acc[i][7] + fb[c1+3]);
            *(float4*)&out[(size_t)node * HID + c0] = o0;
            *(float4*)&out[(size_t)node * HID + c1] = o1;
        }
    }
}

// ---------------- energy head + global sum ----------------
__global__ __launch_bounds__(256) void energy_kernel(
    const float* __restrict__ feats,
    const float* __restrict__ ew1, const float* __restrict__ eb1,
    const float* __restrict__ ew2, const float* __restrict__ eb2,
    float* __restrict__ out)
{
    __shared__ float sA[64][20];
    __shared__ float sB[16][HID];
    __shared__ float sV[HID];
    __shared__ float red[256];
    int tid = threadIdx.x;
    int n0 = blockIdx.x * 64;
    const int tr = tid >> 4, tc = tid & 15;
    const int r0 = tr * 4, c0 = tc * 4, c1 = c0 + 64;
    const int el = tid >> 2, kq = (tid & 3) * 4;

    if (tid < HID) sV[tid] = ew2[tid];

    float acc[4][8];
    #pragma unroll
    for (int i = 0; i < 4; i++)
        #pragma unroll
        for (int j = 0; j < 8; j++) acc[i][j] = 0.f;

    for (int kt = 0; kt < 8; ++kt) {   // K = 128
        int k0 = kt * 16;
        {
            int k = k0 + kq;
            int node = n0 + el;
            float4 v = make_float4(0,0,0,0);
            if (node < N_NODES) v = *(const float4*)&feats[(size_t)node * HID + k];
            *(float4*)&sA[el][kq] = v;
        }
        {
            int bk = tid >> 4, bj = (tid & 15) * 8;
            int k = k0 + bk;
            *(float4*)&sB[bk][bj]     = *(const float4*)&ew1[(size_t)k * HID + bj];
            *(float4*)&sB[bk][bj + 4] = *(const float4*)&ew1[(size_t)k * HID + bj + 4];
        }
        __syncthreads();
        #pragma unroll
        for (int kk4 = 0; kk4 < 4; ++kk4) {
            float4 a0 = *(const float4*)&sA[r0 + 0][kk4 * 4];
            float4 a1 = *(const float4*)&sA[r0 + 1][kk4 * 4];
            float4 a2 = *(const float4*)&sA[r0 + 2][kk4 * 4];
            float4 a3 = *(const float4*)&sA[r0 + 3][kk4 * 4];
            #pragma unroll
            for (int q = 0; q < 4; ++q) {
                int kk = kk4 * 4 + q;
                float4 b0 = *(const float4*)&sB[kk][c0];
                float4 b1 = *(const float4*)&sB[kk][c1];
                float q0 = ((const float*)&a0)[q], q1 = ((const float*)&a1)[q];
                float q2 = ((const float*)&a2)[q], q3 = ((const float*)&a3)[q];
                FMA8(0, q0) FMA8(1, q1) FMA8(2, q2) FMA8(3, q3)
            }
        }
        __syncthreads();
    }
    float part = 0.f;
    #pragma unroll
    for (int i = 0; i < 4; i++) {
        int node = n0 + r0 + i;
        if (node < N_NODES) {
            #pragma unroll
            for (int j = 0; j < 4; j++) {
                part += silu_f(acc[i][j]     + eb1[c0+j]) * sV[c0+j];
                part += silu_f(acc[i][4 + j] + eb1[c1+j]) * sV[c1+j];
            }
        }
    }
    red[tid] = part;
    __syncthreads();
    for (int s = 128; s > 0; s >>= 1) {
        if (tid < s) red[tid] += red[tid + s];
        __syncthreads();
    }
    if (tid == 0) {
        float v = red[0];
        if (blockIdx.x == 0) v += eb2[0] * (float)N_NODES;
        atomicAdd(out, v);
    }
}

// ---------------- launcher ----------------

extern "C" void kernel_launch(void* const* d_in, const int* in_sizes, int n_in,
                              void* d_out, int out_size, void* d_ws, size_t ws_size,
                              hipStream_t stream)
{
    const int*   an     = (const int*)  d_in[0];
    const float* coords = (const float*)d_in[1];
    const int*   ei     = (const int*)  d_in[2];
    const float* embed  = (const float*)d_in[3];
    const float* mw1 = (const float*)d_in[4];
    const float* mb1 = (const float*)d_in[5];
    const float* mw2 = (const float*)d_in[6];
    const float* mb2 = (const float*)d_in[7];
    const float* cw1 = (const float*)d_in[8];
    const float* cb1 = (const float*)d_in[9];
    const float* cw2 = (const float*)d_in[10];
    const float* cb2 = (const float*)d_in[11];
    const float* fw  = (const float*)d_in[12];
    const float* fb  = (const float*)d_in[13];
    const float* ew1 = (const float*)d_in[14];
    const float* eb1 = (const float*)d_in[15];
    const float* ew2 = (const float*)d_in[16];
    const float* eb2 = (const float*)d_in[17];
    float* out = (float*)d_out;

    char* w = (char*)d_ws;
    size_t off = 0;
    auto alloc = [&](size_t bytes) -> char* {
        char* p = w + off;
        off = (off + bytes + 511) & ~(size_t)511;
        return p;
    };
    float* feats0 = (float*)alloc((size_t)N_NODES * HID * 4);
    float* feats1 = (float*)alloc((size_t)N_NODES * HID * 4);
    float* agg    = (float*)alloc((size_t)N_NODES * HID * 4);
    float* cA     = (float*)alloc((size_t)N_NODES * 3 * 4);
    float* cB     = (float*)alloc((size_t)N_NODES * 3 * 4);
    float* d0     = (float*)alloc((size_t)N_EDGES * 4);
    float* cut0   = (float*)alloc((size_t)N_EDGES * 4);
    int*   sorted = (int*)  alloc((size_t)N_EDGES * 4);
    int*   cnt    = (int*)  alloc((size_t)N_NODES * 4);
    int*   cursor = (int*)  alloc((size_t)N_NODES * 4);

    const int* erow = ei;
    const int* ecol = ei + N_EDGES;

    hipMemsetAsync(cnt, 0, (size_t)N_NODES * 4, stream);
    init_feats_kernel<<<(N_NODES * HID + 255) / 256, 256, 0, stream>>>(an, embed, feats0);
    hipMemcpyAsync(cA, coords, (size_t)N_NODES * 3 * 4, hipMemcpyDeviceToDevice, stream);
    hist_kernel<<<(N_EDGES + 255) / 256, 256, 0, stream>>>(erow, cnt);
    scan_kernel<<<1, 256, 0, stream>>>(cnt, cursor);
    scatter_kernel<<<(N_EDGES + 255) / 256, 256, 0, stream>>>(erow, cursor, sorted);
    edgegeom_kernel<<<N_EDGES / 256, 256, 0, stream>>>(sorted, erow, ecol, cA, d0, cut0);

    float* fc = feats0; float* fn = feats1;
    float* cc = cA;     float* cn = cB;
    for (int l = 0; l < N_LAYERS; ++l) {
        hipMemsetAsync(agg, 0, (size_t)N_NODES * HID * 4, stream);
        hipMemcpyAsync(cn, cc, (size_t)N_NODES * 3 * 4, hipMemcpyDeviceToDevice, stream);
        edge_kernel<<<N_EDGES / 64, 256, 0, stream>>>(
            sorted, erow, ecol, cc, cn, fc, d0, cut0,
            mw1 + (size_t)l * EDGE_IN * HID, mb1 + (size_t)l * HID,
            mw2 + (size_t)l * HID * HID,    mb2 + (size_t)l * HID,
            cw1 + (size_t)l * HID * HID,    cb1 + (size_t)l * HID,
            cw2 + (size_t)l * HID,          cb2 + l, agg);
        node_kernel<<<(N_NODES + 63) / 64, 256, 0, stream>>>(
            fc, agg, fw + (size_t)l * 2 * HID * HID, fb + (size_t)l * HID, fn);
        { float* t = fc; fc = fn; fn = t; }
        { float* t = cc; cc = cn; cn = t; }
    }
    hipMemsetAsync(out, 0, 4, stream);
    energy_kernel<<<(N_NODES + 63) / 64, 256, 0, stream>>>(fc, ew1, eb1, ew2, eb2, out);
}

// Round 3
// 1443.159 us; speedup vs baseline: 2.7423x; 2.7423x over previous
//
#include <hip/hip_runtime.h>
#include <math.h>

#define N_NODES  10000
#define N_EDGES  160000
#define HID      128
#define N_LAYERS 6
#define N_RBF    50
#define EDGE_IN  307     // 2*HID + 1 + N_RBF
#define KP1      320     // phase-1 K padded (stride of wtm1)

typedef short bf16x8 __attribute__((ext_vector_type(8)));
typedef float f32x4  __attribute__((ext_vector_type(4)));

__device__ __forceinline__ float silu_f(float x) {
    return x / (1.0f + __expf(-x));
}
__device__ __forceinline__ short f2bf(float f) {
    union { float f; unsigned u; } v; v.f = f;
    unsigned r = v.u + 0x7FFFu + ((v.u >> 16) & 1u);   // RNE
    return (short)(r >> 16);
}
__device__ __forceinline__ float bf2f(unsigned short s) {
    union { float f; unsigned u; } v; v.u = ((unsigned)s) << 16;
    return v.f;
}

// ---------------- setup kernels ----------------

__global__ void init_feats_kernel(const int* __restrict__ an,
                                  const float* __restrict__ embed,
                                  short* __restrict__ featsB) {
    int idx = blockIdx.x * blockDim.x + threadIdx.x;
    if (idx < N_NODES * HID) {
        int i = idx >> 7, j = idx & 127;
        featsB[idx] = f2bf(embed[an[i] * HID + j]);
    }
}

__global__ void hist_kernel(const int* __restrict__ row, int* __restrict__ cnt) {
    int e = blockIdx.x * blockDim.x + threadIdx.x;
    if (e < N_EDGES) atomicAdd(&cnt[row[e]], 1);
}

__global__ void scan_kernel(const int* __restrict__ cnt, int* __restrict__ cursor) {
    __shared__ int buf[256];
    __shared__ int carry;
    int tid = threadIdx.x;
    if (tid == 0) carry = 0;
    __syncthreads();
    for (int base = 0; base < N_NODES; base += 256) {
        int v = (base + tid < N_NODES) ? cnt[base + tid] : 0;
        buf[tid] = v;
        __syncthreads();
        for (int off = 1; off < 256; off <<= 1) {
            int x = (tid >= off) ? buf[tid - off] : 0;
            __syncthreads();
            buf[tid] += x;
            __syncthreads();
        }
        int excl = buf[tid] - v + carry;
        if (base + tid < N_NODES) cursor[base + tid] = excl;
        int tot = buf[255];
        __syncthreads();
        if (tid == 0) carry += tot;
        __syncthreads();
    }
}

__global__ void scatter_kernel(const int* __restrict__ row, int* __restrict__ cursor,
                               int* __restrict__ sorted) {
    int e = blockIdx.x * blockDim.x + threadIdx.x;
    if (e < N_EDGES) {
        int p = atomicAdd(&cursor[row[e]], 1);
        sorted[p] = e;
    }
}

__global__ void edgegeom_kernel(const int* __restrict__ sorted,
                                const int* __restrict__ erow, const int* __restrict__ ecol,
                                const float* __restrict__ coords,
                                float* __restrict__ d0, float* __restrict__ cut0) {
    int p = blockIdx.x * 256 + threadIdx.x;
    if (p < N_EDGES) {
        int e = sorted[p];
        int r = erow[e], c = ecol[e];
        float dx = coords[3*r]   - coords[3*c];
        float dy = coords[3*r+1] - coords[3*c+1];
        float dz = coords[3*r+2] - coords[3*c+2];
        float d = sqrtf(dx*dx + dy*dy + dz*dz);
        d0[p] = d;
        cut0[p] = (d < 10.0f) ? 0.5f * (__cosf(0.31415926535f * d) + 1.0f) : 0.0f;
    }
}

// weight transpose+cast: Bt[n][k] bf16 for all layers of mw1/mw2/cw1/fw
// per-layer sizes: m1 128*320=40960, m2 128*128=16384, c1 16384, f 128*256=32768
#define WT_L (40960 + 16384 + 16384 + 32768)   // 106496
__global__ void wtrans_kernel(const float* __restrict__ mw1, const float* __restrict__ mw2,
                              const float* __restrict__ cw1, const float* __restrict__ fw,
                              short* __restrict__ wtm1, short* __restrict__ wtm2,
                              short* __restrict__ wtc1, short* __restrict__ wtf) {
    int idx = blockIdx.x * blockDim.x + threadIdx.x;
    if (idx >= N_LAYERS * WT_L) return;
    int l = idx / WT_L;
    int r = idx - l * WT_L;
    if (r < 40960) {
        int n = r / KP1, k = r - n * KP1;
        float v = (k < EDGE_IN) ? mw1[(size_t)l * EDGE_IN * HID + (size_t)k * HID + n] : 0.f;
        wtm1[(size_t)l * 40960 + r] = f2bf(v);
    } else if ((r -= 40960) < 16384) {
        int n = r >> 7, k = r & 127;
        wtm2[(size_t)l * 16384 + r] = f2bf(mw2[(size_t)l * HID * HID + (size_t)k * HID + n]);
    } else if ((r -= 16384) < 16384) {
        int n = r >> 7, k = r & 127;
        wtc1[(size_t)l * 16384 + r] = f2bf(cw1[(size_t)l * HID * HID + (size_t)k * HID + n]);
    } else {
        r -= 16384;
        int n = r >> 8, k = r & 255;
        wtf[(size_t)l * 32768 + r] = f2bf(fw[(size_t)l * 2 * HID * HID + (size_t)k * HID + n]);
    }
}

// ---------------- fused per-layer edge kernel (MFMA bf16) ----------------
// tile: 64 sorted edges x 128 cols, 256 threads = 4 waves; wave w owns rows 16w..16w+15

__global__ __launch_bounds__(256) void edge_kernel(
    const int* __restrict__ sorted,
    const int* __restrict__ erow, const int* __restrict__ ecol,
    const float* __restrict__ coords, float* __restrict__ coords_next,
    const short* __restrict__ featsB,
    const float* __restrict__ d0g, const float* __restrict__ cut0g,
    const short* __restrict__ wtm1, const float* __restrict__ mb1,
    const short* __restrict__ wtm2, const float* __restrict__ mb2,
    const short* __restrict__ wtc1, const float* __restrict__ cb1,
    const float* __restrict__ cw2, const float* __restrict__ cb2,
    float* __restrict__ agg)
{
    __shared__ short sA[64][72];        // A K-chunk staging (stride 144B: ~2-way max)
    __shared__ short sH[64][136];       // h1 -> m, bf16, wave-private rows
    __shared__ int   srow[64];
    __shared__ int   scol[64];
    __shared__ float sdiff[64][3];
    __shared__ float sdist[64], sd0[64], scut[64], sW[64];
    __shared__ float sWp[64][17];
    __shared__ float sB1[HID], sB2[HID], sC1[HID], sV[HID];

    const int tid = threadIdx.x;
    const int p0 = blockIdx.x * 64;
    const int wave = tid >> 6, lane = tid & 63, quad = lane >> 4, lm = lane & 15;
    const int mrow = wave * 16 + lm;          // A-frag row
    const int rbase = wave * 16 + quad * 4;   // C-frag rows rbase..rbase+3

    if (tid < 64) {
        int e = sorted[p0 + tid];
        int r = erow[e], c = ecol[e];
        srow[tid] = r; scol[tid] = c;
        float dx = coords[3*r]   - coords[3*c];
        float dy = coords[3*r+1] - coords[3*c+1];
        float dz = coords[3*r+2] - coords[3*c+2];
        sdiff[tid][0] = dx; sdiff[tid][1] = dy; sdiff[tid][2] = dz;
        sdist[tid] = dx*dx + dy*dy + dz*dz;
        sd0[tid]  = d0g[p0 + tid];
        scut[tid] = cut0g[p0 + tid];
    }
    if (tid < HID) {
        sB1[tid] = mb1[tid]; sB2[tid] = mb2[tid];
        sC1[tid] = cb1[tid]; sV[tid]  = cw2[tid];
    }
    __syncthreads();

    f32x4 acc[8];
    #pragma unroll
    for (int nb = 0; nb < 8; ++nb) acc[nb] = (f32x4)0.f;

    // ---- phase 1: h1 = silu(ef @ mw1 + mb1), K = 320, 5 chunks of 64 ----
    for (int c = 0; c < 5; ++c) {
        int k0 = c * 64;
        {   // stage A chunk: 64 rows x 64 k, bf16
            int el = tid >> 2, kq = (tid & 3) * 16;
            if (c < 4) {
                int node = (c < 2) ? srow[el] : scol[el];
                int off = (k0 & 127) + kq;
                const bf16x8* src = (const bf16x8*)&featsB[(size_t)node * HID + off];
                *(bf16x8*)&sA[el][kq]     = src[0];
                *(bf16x8*)&sA[el][kq + 8] = src[1];
            } else {
                float dv = sd0[el], ct = scut[el], ds2 = sdist[el];
                #pragma unroll
                for (int j = 0; j < 16; ++j) {
                    int k = 256 + kq + j;
                    float v = 0.f;
                    if (k == 256) v = ds2;
                    else if (k < EDGE_IN) {
                        float cen = (float)(k - 257) * (10.0f / 49.0f);
                        float t = dv - cen;
                        v = __expf(-t * t * 5.0f) * ct;
                    }
                    sA[el][kq + j] = f2bf(v);
                }
            }
        }
        __syncthreads();
        #pragma unroll
        for (int h = 0; h < 2; ++h) {
            bf16x8 af = *(bf16x8*)&sA[mrow][h * 32 + quad * 8];
            const short* bb = wtm1 + (k0 + h * 32 + quad * 8);
            #pragma unroll
            for (int nb = 0; nb < 8; ++nb) {
                bf16x8 bf = *(const bf16x8*)&bb[(size_t)(nb * 16 + lm) * KP1];
                acc[nb] = __builtin_amdgcn_mfma_f32_16x16x32_bf16(af, bf, acc[nb], 0, 0, 0);
            }
        }
        __syncthreads();
    }
    // epilogue 1: silu + bias -> sH (wave-private rows, no barrier needed)
    #pragma unroll
    for (int nb = 0; nb < 8; ++nb) {
        int col = nb * 16 + lm;
        float b = sB1[col];
        #pragma unroll
        for (int r = 0; r < 4; ++r)
            sH[rbase + r][col] = f2bf(silu_f(acc[nb][r] + b));
        acc[nb] = (f32x4)0.f;
    }

    // ---- phase 2: m = silu(h1 @ mw2 + mb2), K = 128 ----
    #pragma unroll
    for (int ks = 0; ks < 4; ++ks) {
        bf16x8 af = *(bf16x8*)&sH[mrow][ks * 32 + quad * 8];
        const short* bb = wtm2 + (ks * 32 + quad * 8);
        #pragma unroll
        for (int nb = 0; nb < 8; ++nb) {
            bf16x8 bf = *(const bf16x8*)&bb[(size_t)(nb * 16 + lm) * HID];
            acc[nb] = __builtin_amdgcn_mfma_f32_16x16x32_bf16(af, bf, acc[nb], 0, 0, 0);
        }
    }
    // epilogue 2: silu+bias in-place; run-reduce scatter to agg (fp32 atomics)
    #pragma unroll
    for (int nb = 0; nb < 8; ++nb) {
        int col = nb * 16 + lm;
        float b = sB2[col];
        float g = 0.f;
        #pragma unroll
        for (int r = 0; r < 4; ++r) {
            float mv = silu_f(acc[nb][r] + b);
            acc[nb][r] = mv;
            g += mv;
            int row = rbase + r;
            if (r == 3 || srow[row + 1] != srow[row]) {
                atomicAdd(&agg[(size_t)srow[row] * HID + col], g);
                g = 0.f;
            }
        }
    }
    // write m bf16 -> sH (wave-private; same wave just read these rows)
    #pragma unroll
    for (int nb = 0; nb < 8; ++nb) {
        int col = nb * 16 + lm;
        #pragma unroll
        for (int r = 0; r < 4; ++r)
            sH[rbase + r][col] = f2bf(acc[nb][r]);
        acc[nb] = (f32x4)0.f;
    }

    // ---- phase 3: c1 = silu(m @ cw1 + cb1), K = 128 ----
    #pragma unroll
    for (int ks = 0; ks < 4; ++ks) {
        bf16x8 af = *(bf16x8*)&sH[mrow][ks * 32 + quad * 8];
        const short* bb = wtc1 + (ks * 32 + quad * 8);
        #pragma unroll
        for (int nb = 0; nb < 8; ++nb) {
            bf16x8 bf = *(const bf16x8*)&bb[(size_t)(nb * 16 + lm) * HID];
            acc[nb] = __builtin_amdgcn_mfma_f32_16x16x32_bf16(af, bf, acc[nb], 0, 0, 0);
        }
    }
    // epilogue 3: w = c1 . cw2 + cb2 (partial over this lane's 8 cols)
    {
        float p[4] = {0.f, 0.f, 0.f, 0.f};
        #pragma unroll
        for (int nb = 0; nb < 8; ++nb) {
            int col = nb * 16 + lm;
            float b = sC1[col], vv = sV[col];
            #pragma unroll
            for (int r = 0; r < 4; ++r)
                p[r] += silu_f(acc[nb][r] + b) * vv;
        }
        #pragma unroll
        for (int r = 0; r < 4; ++r) sWp[rbase + r][lm] = p[r];
    }
    __syncthreads();
    if (tid < 64) {
        float w = cb2[0];
        #pragma unroll
        for (int j = 0; j < 16; ++j) w += sWp[tid][j];
        sW[tid] = w;
    }
    __syncthreads();
    // coords update: per-run leader, 3 atomics per distinct row
    if (tid < 64) {
        bool leader = (tid == 0) || (srow[tid] != srow[tid - 1]);
        if (leader) {
            int rr = srow[tid];
            float ax = 0.f, ay = 0.f, az = 0.f;
            for (int k = tid; k < 64 && srow[k] == rr; ++k) {
                ax += sW[k] * sdiff[k][0];
                ay += sW[k] * sdiff[k][1];
                az += sW[k] * sdiff[k][2];
            }
            atomicAdd(&coords_next[3*rr+0], ax);
            atomicAdd(&coords_next[3*rr+1], ay);
            atomicAdd(&coords_next[3*rr+2], az);
        }
    }
}

// ---------------- node update (MFMA): feats' = silu([feats|agg] @ fw + fb) ----------------
__global__ __launch_bounds__(256) void node_kernel(
    const short* __restrict__ featsB, const float* __restrict__ agg,
    const short* __restrict__ wtf, const float* __restrict__ fb,
    short* __restrict__ outB)
{
    __shared__ short sA[64][72];
    __shared__ short sO[64][136];
    __shared__ float sFb[HID];

    const int tid = threadIdx.x;
    const int n0 = blockIdx.x * 64;
    const int wave = tid >> 6, lane = tid & 63, quad = lane >> 4, lm = lane & 15;
    const int mrow = wave * 16 + lm;
    const int rbase = wave * 16 + quad * 4;

    if (tid < HID) sFb[tid] = fb[tid];

    f32x4 acc[8];
    #pragma unroll
    for (int nb = 0; nb < 8; ++nb) acc[nb] = (f32x4)0.f;
    __syncthreads();

    for (int c = 0; c < 4; ++c) {   // K = 256, 4 chunks of 64
        int k0 = c * 64;
        {
            int el = tid >> 2, kq = (tid & 3) * 16;
            int node = n0 + el;
            if (node < N_NODES) {
                if (c < 2) {
                    const bf16x8* src = (const bf16x8*)&featsB[(size_t)node * HID + k0 + kq];
                    *(bf16x8*)&sA[el][kq]     = src[0];
                    *(bf16x8*)&sA[el][kq + 8] = src[1];
                } else {
                    const float* ap = &agg[(size_t)node * HID + (k0 - 128) + kq];
                    #pragma unroll
                    for (int j = 0; j < 16; ++j) sA[el][kq + j] = f2bf(ap[j]);
                }
            } else {
                #pragma unroll
                for (int j = 0; j < 16; ++j) sA[el][kq + j] = 0;
            }
        }
        __syncthreads();
        #pragma unroll
        for (int h = 0; h < 2; ++h) {
            bf16x8 af = *(bf16x8*)&sA[mrow][h * 32 + quad * 8];
            const short* bb = wtf + (k0 + h * 32 + quad * 8);
            #pragma unroll
            for (int nb = 0; nb < 8; ++nb) {
                bf16x8 bf = *(const bf16x8*)&bb[(size_t)(nb * 16 + lm) * 256];
                acc[nb] = __builtin_amdgcn_mfma_f32_16x16x32_bf16(af, bf, acc[nb], 0, 0, 0);
            }
        }
        __syncthreads();
    }
    #pragma unroll
    for (int nb = 0; nb < 8; ++nb) {
        int col = nb * 16 + lm;
        float b = sFb[col];
        #pragma unroll
        for (int r = 0; r < 4; ++r)
            sO[rbase + r][col] = f2bf(silu_f(acc[nb][r] + b));
    }
    __syncthreads();
    {   // cooperative coalesced bf16 write
        int row = tid >> 2, ch = (tid & 3) * 32;
        int node = n0 + row;
        if (node < N_NODES) {
            #pragma unroll
            for (int i = 0; i < 4; ++i)
                *(bf16x8*)&outB[(size_t)node * HID + ch + i * 8] = *(bf16x8*)&sO[row][ch + i * 8];
        }
    }
}

// ---------------- energy head + global sum (fp32 VALU, reads bf16 feats) ----------------
#define FMA8(r, aq) \
    acc[r][0] += (aq)*b0.x; acc[r][1] += (aq)*b0.y; acc[r][2] += (aq)*b0.z; acc[r][3] += (aq)*b0.w; \
    acc[r][4] += (aq)*b1.x; acc[r][5] += (aq)*b1.y; acc[r][6] += (aq)*b1.z; acc[r][7] += (aq)*b1.w;

__global__ __launch_bounds__(256) void energy_kernel(
    const short* __restrict__ featsB,
    const float* __restrict__ ew1, const float* __restrict__ eb1,
    const float* __restrict__ ew2, const float* __restrict__ eb2,
    float* __restrict__ out)
{
    __shared__ float sA[64][20];
    __shared__ float sB[16][HID];
    __shared__ float sV[HID];
    __shared__ float red[256];
    int tid = threadIdx.x;
    int n0 = blockIdx.x * 64;
    const int tr = tid >> 4, tc = tid & 15;
    const int r0 = tr * 4, c0 = tc * 4, c1 = c0 + 64;
    const int el = tid >> 2, kq = (tid & 3) * 4;

    if (tid < HID) sV[tid] = ew2[tid];

    float acc[4][8];
    #pragma unroll
    for (int i = 0; i < 4; i++)
        #pragma unroll
        for (int j = 0; j < 8; j++) acc[i][j] = 0.f;

    for (int kt = 0; kt < 8; ++kt) {   // K = 128
        int k0 = kt * 16;
        {
            int k = k0 + kq;
            int node = n0 + el;
            float4 v = make_float4(0,0,0,0);
            if (node < N_NODES) {
                const unsigned short* p = (const unsigned short*)&featsB[(size_t)node * HID + k];
                v.x = bf2f(p[0]); v.y = bf2f(p[1]); v.z = bf2f(p[2]); v.w = bf2f(p[3]);
            }
            *(float4*)&sA[el][kq] = v;
        }
        {
            int bk = tid >> 4, bj = (tid & 15) * 8;
            int k = k0 + bk;
            *(float4*)&sB[bk][bj]     = *(const float4*)&ew1[(size_t)k * HID + bj];
            *(float4*)&sB[bk][bj + 4] = *(const float4*)&ew1[(size_t)k * HID + bj + 4];
        }
        __syncthreads();
        #pragma unroll
        for (int kk4 = 0; kk4 < 4; ++kk4) {
            float4 a0 = *(const float4*)&sA[r0 + 0][kk4 * 4];
            float4 a1 = *(const float4*)&sA[r0 + 1][kk4 * 4];
            float4 a2 = *(const float4*)&sA[r0 + 2][kk4 * 4];
            float4 a3 = *(const float4*)&sA[r0 + 3][kk4 * 4];
            #pragma unroll
            for (int q = 0; q < 4; ++q) {
                int kk = kk4 * 4 + q;
                float4 b0 = *(const float4*)&sB[kk][c0];
                float4 b1 = *(const float4*)&sB[kk][c1];
                float q0 = ((const float*)&a0)[q], q1 = ((const float*)&a1)[q];
                float q2 = ((const float*)&a2)[q], q3 = ((const float*)&a3)[q];
                FMA8(0, q0) FMA8(1, q1) FMA8(2, q2) FMA8(3, q3)
            }
        }
        __syncthreads();
    }
    float part = 0.f;
    #pragma unroll
    for (int i = 0; i < 4; i++) {
        int node = n0 + r0 + i;
        if (node < N_NODES) {
            #pragma unroll
            for (int j = 0; j < 4; j++) {
                part += silu_f(acc[i][j]     + eb1[c0+j]) * sV[c0+j];
                part += silu_f(acc[i][4 + j] + eb1[c1+j]) * sV[c1+j];
            }
        }
    }
    red[tid] = part;
    __syncthreads();
    for (int s = 128; s > 0; s >>= 1) {
        if (tid < s) red[tid] += red[tid + s];
        __syncthreads();
    }
    if (tid == 0) {
        float v = red[0];
        if (blockIdx.x == 0) v += eb2[0] * (float)N_NODES;
        atomicAdd(out, v);
    }
}

// ---------------- launcher ----------------

extern "C" void kernel_launch(void* const* d_in, const int* in_sizes, int n_in,
                              void* d_out, int out_size, void* d_ws, size_t ws_size,
                              hipStream_t stream)
{
    const int*   an     = (const int*)  d_in[0];
    const float* coords = (const float*)d_in[1];
    const int*   ei     = (const int*)  d_in[2];
    const float* embed  = (const float*)d_in[3];
    const float* mw1 = (const float*)d_in[4];
    const float* mb1 = (const float*)d_in[5];
    const float* mw2 = (const float*)d_in[6];
    const float* mb2 = (const float*)d_in[7];
    const float* cw1 = (const float*)d_in[8];
    const float* cb1 = (const float*)d_in[9];
    const float* cw2 = (const float*)d_in[10];
    const float* cb2 = (const float*)d_in[11];
    const float* fw  = (const float*)d_in[12];
    const float* fb  = (const float*)d_in[13];
    const float* ew1 = (const float*)d_in[14];
    const float* eb1 = (const float*)d_in[15];
    const float* ew2 = (const float*)d_in[16];
    const float* eb2 = (const float*)d_in[17];
    float* out = (float*)d_out;

    char* w = (char*)d_ws;
    size_t off = 0;
    auto alloc = [&](size_t bytes) -> char* {
        char* p = w + off;
        off = (off + bytes + 511) & ~(size_t)511;
        return p;
    };
    short* featsB0 = (short*)alloc((size_t)N_NODES * HID * 2);
    short* featsB1 = (short*)alloc((size_t)N_NODES * HID * 2);
    float* agg     = (float*)alloc((size_t)N_NODES * HID * 4);
    float* cA      = (float*)alloc((size_t)N_NODES * 3 * 4);
    float* cB      = (float*)alloc((size_t)N_NODES * 3 * 4);
    float* d0      = (float*)alloc((size_t)N_EDGES * 4);
    float* cut0    = (float*)alloc((size_t)N_EDGES * 4);
    int*   sorted  = (int*)  alloc((size_t)N_EDGES * 4);
    int*   cnt     = (int*)  alloc((size_t)N_NODES * 4);
    int*   cursor  = (int*)  alloc((size_t)N_NODES * 4);
    short* wtm1    = (short*)alloc((size_t)N_LAYERS * 40960 * 2);
    short* wtm2    = (short*)alloc((size_t)N_LAYERS * 16384 * 2);
    short* wtc1    = (short*)alloc((size_t)N_LAYERS * 16384 * 2);
    short* wtf     = (short*)alloc((size_t)N_LAYERS * 32768 * 2);

    const int* erow = ei;
    const int* ecol = ei + N_EDGES;

    hipMemsetAsync(cnt, 0, (size_t)N_NODES * 4, stream);
    init_feats_kernel<<<(N_NODES * HID + 255) / 256, 256, 0, stream>>>(an, embed, featsB0);
    wtrans_kernel<<<(N_LAYERS * WT_L + 255) / 256, 256, 0, stream>>>(
        mw1, mw2, cw1, fw, wtm1, wtm2, wtc1, wtf);
    hipMemcpyAsync(cA, coords, (size_t)N_NODES * 3 * 4, hipMemcpyDeviceToDevice, stream);
    hist_kernel<<<(N_EDGES + 255) / 256, 256, 0, stream>>>(erow, cnt);
    scan_kernel<<<1, 256, 0, stream>>>(cnt, cursor);
    scatter_kernel<<<(N_EDGES + 255) / 256, 256, 0, stream>>>(erow, cursor, sorted);
    edgegeom_kernel<<<N_EDGES / 256, 256, 0, stream>>>(sorted, erow, ecol, cA, d0, cut0);

    short* fc = featsB0; short* fn = featsB1;
    float* cc = cA;      float* cn = cB;
    for (int l = 0; l < N_LAYERS; ++l) {
        hipMemsetAsync(agg, 0, (size_t)N_NODES * HID * 4, stream);
        hipMemcpyAsync(cn, cc, (size_t)N_NODES * 3 * 4, hipMemcpyDeviceToDevice, stream);
        edge_kernel<<<N_EDGES / 64, 256, 0, stream>>>(
            sorted, erow, ecol, cc, cn, fc, d0, cut0,
            wtm1 + (size_t)l * 40960, mb1 + (size_t)l * HID,
            wtm2 + (size_t)l * 16384, mb2 + (size_t)l * HID,
            wtc1 + (size_t)l * 16384, cb1 + (size_t)l * HID,
            cw2 + (size_t)l * HID,    cb2 + l, agg);
        node_kernel<<<(N_NODES + 63) / 64, 256, 0, stream>>>(
            fc, agg, wtf + (size_t)l * 32768, fb + (size_t)l * HID, fn);
        { short* t = fc; fc = fn; fn = t; }
        { float* t = cc; cc = cn; cn = t; }
    }
    hipMemsetAsync(out, 0, 4, stream);
    energy_kernel<<<(N_NODES + 63) / 64, 256, 0, stream>>>(fc, ew1, eb1, ew2, eb2, out);
}

// Round 4
// 802.189 us; speedup vs baseline: 4.9334x; 1.7990x over previous
//
#include <hip/hip_runtime.h>
#include <math.h>

#define N_NODES  10000
#define N_EDGES  160000
#define HID      128
#define N_LAYERS 6
#define N_RBF    50
#define EDGE_IN  307     // 2*HID + 1 + N_RBF
#define KP1      320     // phase-1 K padded (stride of wtm1)

typedef short bf16x8 __attribute__((ext_vector_type(8)));
typedef float f32x4  __attribute__((ext_vector_type(4)));

__device__ __forceinline__ float silu_f(float x) {
    return x / (1.0f + __expf(-x));
}
__device__ __forceinline__ short f2bf(float f) {
    union { float f; unsigned u; } v; v.f = f;
    unsigned r = v.u + 0x7FFFu + ((v.u >> 16) & 1u);   // RNE
    return (short)(r >> 16);
}
__device__ __forceinline__ float bf2f(unsigned short s) {
    union { float f; unsigned u; } v; v.u = ((unsigned)s) << 16;
    return v.f;
}

// ---------------- setup kernels ----------------

__global__ void init_feats_kernel(const int* __restrict__ an,
                                  const float* __restrict__ embed,
                                  short* __restrict__ featsB) {
    int idx = blockIdx.x * blockDim.x + threadIdx.x;
    if (idx < N_NODES * HID) {
        int i = idx >> 7, j = idx & 127;
        featsB[idx] = f2bf(embed[an[i] * HID + j]);
    }
}

__global__ void hist_kernel(const int* __restrict__ row, int* __restrict__ cnt) {
    int e = blockIdx.x * blockDim.x + threadIdx.x;
    if (e < N_EDGES) atomicAdd(&cnt[row[e]], 1);
}

__global__ void scan_kernel(const int* __restrict__ cnt, int* __restrict__ cursor) {
    __shared__ int buf[256];
    __shared__ int carry;
    int tid = threadIdx.x;
    if (tid == 0) carry = 0;
    __syncthreads();
    for (int base = 0; base < N_NODES; base += 256) {
        int v = (base + tid < N_NODES) ? cnt[base + tid] : 0;
        buf[tid] = v;
        __syncthreads();
        for (int off = 1; off < 256; off <<= 1) {
            int x = (tid >= off) ? buf[tid - off] : 0;
            __syncthreads();
            buf[tid] += x;
            __syncthreads();
        }
        int excl = buf[tid] - v + carry;
        if (base + tid < N_NODES) cursor[base + tid] = excl;
        int tot = buf[255];
        __syncthreads();
        if (tid == 0) carry += tot;
        __syncthreads();
    }
}

__global__ void scatter_kernel(const int* __restrict__ row, int* __restrict__ cursor,
                               int* __restrict__ sorted) {
    int e = blockIdx.x * blockDim.x + threadIdx.x;
    if (e < N_EDGES) {
        int p = atomicAdd(&cursor[row[e]], 1);
        sorted[p] = e;
    }
}

__global__ void edgegeom_kernel(const int* __restrict__ sorted,
                                const int* __restrict__ erow, const int* __restrict__ ecol,
                                const float* __restrict__ coords,
                                float* __restrict__ d0, float* __restrict__ cut0) {
    int p = blockIdx.x * 256 + threadIdx.x;
    if (p < N_EDGES) {
        int e = sorted[p];
        int r = erow[e], c = ecol[e];
        float dx = coords[3*r]   - coords[3*c];
        float dy = coords[3*r+1] - coords[3*c+1];
        float dz = coords[3*r+2] - coords[3*c+2];
        float d = sqrtf(dx*dx + dy*dy + dz*dz);
        d0[p] = d;
        cut0[p] = (d < 10.0f) ? 0.5f * (__cosf(0.31415926535f * d) + 1.0f) : 0.0f;
    }
}

// weight transpose+cast: Bt[n][k] bf16 for all layers of mw1/mw2/cw1/fw
#define WT_L (40960 + 16384 + 16384 + 32768)   // 106496
__global__ void wtrans_kernel(const float* __restrict__ mw1, const float* __restrict__ mw2,
                              const float* __restrict__ cw1, const float* __restrict__ fw,
                              short* __restrict__ wtm1, short* __restrict__ wtm2,
                              short* __restrict__ wtc1, short* __restrict__ wtf) {
    int idx = blockIdx.x * blockDim.x + threadIdx.x;
    if (idx >= N_LAYERS * WT_L) return;
    int l = idx / WT_L;
    int r = idx - l * WT_L;
    if (r < 40960) {
        int n = r / KP1, k = r - n * KP1;
        float v = (k < EDGE_IN) ? mw1[(size_t)l * EDGE_IN * HID + (size_t)k * HID + n] : 0.f;
        wtm1[(size_t)l * 40960 + r] = f2bf(v);
    } else if ((r -= 40960) < 16384) {
        int n = r >> 7, k = r & 127;
        wtm2[(size_t)l * 16384 + r] = f2bf(mw2[(size_t)l * HID * HID + (size_t)k * HID + n]);
    } else if ((r -= 16384) < 16384) {
        int n = r >> 7, k = r & 127;
        wtc1[(size_t)l * 16384 + r] = f2bf(cw1[(size_t)l * HID * HID + (size_t)k * HID + n]);
    } else {
        r -= 16384;
        int n = r >> 8, k = r & 255;
        wtf[(size_t)l * 32768 + r] = f2bf(fw[(size_t)l * 2 * HID * HID + (size_t)k * HID + n]);
    }
}

// ---------------- fused per-layer edge kernel (MFMA bf16, col-split waves) ----------------
// tile: 64 sorted edges x 128 cols; 4 waves; wave w owns cols [32w, 32w+32);
// each wave spans all 64 rows as 4 m-tiles -> each B-frag load feeds 4 MFMAs.

__global__ __launch_bounds__(256) void edge_kernel(
    const int* __restrict__ sorted,
    const int* __restrict__ erow, const int* __restrict__ ecol,
    const float* __restrict__ coords, float* __restrict__ coords_next,
    const short* __restrict__ featsB,
    const float* __restrict__ d0g, const float* __restrict__ cut0g,
    const short* __restrict__ wtm1, const float* __restrict__ mb1,
    const short* __restrict__ wtm2, const float* __restrict__ mb2,
    const short* __restrict__ wtc1, const float* __restrict__ cb1,
    const float* __restrict__ cw2, const float* __restrict__ cb2,
    float* __restrict__ agg)
{
    __shared__ short sA[64][72];        // A K-chunk staging
    __shared__ short sH[64][136];       // h1 -> m -> c1 (bf16)
    __shared__ int   srow[64];
    __shared__ int   scol[64];
    __shared__ float sdiff[64][3];
    __shared__ float sdist[64], sd0[64], scut[64], sW[64];
    __shared__ float sB1[HID], sB2[HID], sC1[HID], sV[HID];

    const int tid = threadIdx.x;
    const int p0 = blockIdx.x * 64;
    const int wave = tid >> 6, lane = tid & 63, quad = lane >> 4, lm = lane & 15;
    // lane's C columns: wcol0 = wave*32 + nb*16 + lm (nb in {0,1})

    if (tid < 64) {
        int e = sorted[p0 + tid];
        int r = erow[e], c = ecol[e];
        srow[tid] = r; scol[tid] = c;
        float dx = coords[3*r]   - coords[3*c];
        float dy = coords[3*r+1] - coords[3*c+1];
        float dz = coords[3*r+2] - coords[3*c+2];
        sdiff[tid][0] = dx; sdiff[tid][1] = dy; sdiff[tid][2] = dz;
        sdist[tid] = dx*dx + dy*dy + dz*dz;
        sd0[tid]  = d0g[p0 + tid];
        scut[tid] = cut0g[p0 + tid];
    }
    if (tid < HID) {
        sB1[tid] = mb1[tid]; sB2[tid] = mb2[tid];
        sC1[tid] = cb1[tid]; sV[tid]  = cw2[tid];
    }
    __syncthreads();

    f32x4 acc[4][2];
    #pragma unroll
    for (int mt = 0; mt < 4; ++mt) { acc[mt][0] = (f32x4)0.f; acc[mt][1] = (f32x4)0.f; }

    // ---- phase 1: h1 = silu(ef @ mw1 + mb1), K = 320, 5 chunks of 64 ----
    for (int c = 0; c < 5; ++c) {
        int k0 = c * 64;
        {   // stage A chunk: 64 rows x 64 k, bf16
            int el = tid >> 2, kq = (tid & 3) * 16;
            if (c < 4) {
                int node = (c < 2) ? srow[el] : scol[el];
                int off = (k0 & 127) + kq;
                const bf16x8* src = (const bf16x8*)&featsB[(size_t)node * HID + off];
                *(bf16x8*)&sA[el][kq]     = src[0];
                *(bf16x8*)&sA[el][kq + 8] = src[1];
            } else {
                float dv = sd0[el], ct = scut[el], ds2 = sdist[el];
                #pragma unroll
                for (int j = 0; j < 16; ++j) {
                    int k = 256 + kq + j;
                    float v = 0.f;
                    if (k == 256) v = ds2;
                    else if (k < EDGE_IN) {
                        float cen = (float)(k - 257) * (10.0f / 49.0f);
                        float t = dv - cen;
                        v = __expf(-t * t * 5.0f) * ct;
                    }
                    sA[el][kq + j] = f2bf(v);
                }
            }
        }
        __syncthreads();
        #pragma unroll
        for (int h = 0; h < 2; ++h) {
            bf16x8 af[4];
            #pragma unroll
            for (int mt = 0; mt < 4; ++mt)
                af[mt] = *(bf16x8*)&sA[mt * 16 + lm][h * 32 + quad * 8];
            #pragma unroll
            for (int nb = 0; nb < 2; ++nb) {
                int col = wave * 32 + nb * 16 + lm;
                bf16x8 bf = *(const bf16x8*)&wtm1[(size_t)col * KP1 + k0 + h * 32 + quad * 8];
                #pragma unroll
                for (int mt = 0; mt < 4; ++mt)
                    acc[mt][nb] = __builtin_amdgcn_mfma_f32_16x16x32_bf16(af[mt], bf, acc[mt][nb], 0, 0, 0);
            }
        }
        __syncthreads();
    }
    // epilogue 1: silu + bias -> sH
    #pragma unroll
    for (int nb = 0; nb < 2; ++nb) {
        int col = wave * 32 + nb * 16 + lm;
        float b = sB1[col];
        #pragma unroll
        for (int mt = 0; mt < 4; ++mt) {
            #pragma unroll
            for (int r = 0; r < 4; ++r)
                sH[mt * 16 + quad * 4 + r][col] = f2bf(silu_f(acc[mt][nb][r] + b));
            acc[mt][nb] = (f32x4)0.f;
        }
    }
    __syncthreads();

    // ---- phase 2: m = silu(h1 @ mw2 + mb2), K = 128 ----
    #pragma unroll
    for (int ks = 0; ks < 4; ++ks) {
        bf16x8 af[4];
        #pragma unroll
        for (int mt = 0; mt < 4; ++mt)
            af[mt] = *(bf16x8*)&sH[mt * 16 + lm][ks * 32 + quad * 8];
        #pragma unroll
        for (int nb = 0; nb < 2; ++nb) {
            int col = wave * 32 + nb * 16 + lm;
            bf16x8 bf = *(const bf16x8*)&wtm2[(size_t)col * HID + ks * 32 + quad * 8];
            #pragma unroll
            for (int mt = 0; mt < 4; ++mt)
                acc[mt][nb] = __builtin_amdgcn_mfma_f32_16x16x32_bf16(af[mt], bf, acc[mt][nb], 0, 0, 0);
        }
    }
    __syncthreads();   // all phase-2 reads of sH complete before m overwrite
    // epilogue 2: silu+bias; run-reduce scatter to agg; write m (bf16) -> sH
    #pragma unroll
    for (int nb = 0; nb < 2; ++nb) {
        int col = wave * 32 + nb * 16 + lm;
        float b = sB2[col];
        #pragma unroll
        for (int mt = 0; mt < 4; ++mt) {
            float g = 0.f;
            #pragma unroll
            for (int r = 0; r < 4; ++r) {
                int row = mt * 16 + quad * 4 + r;
                float mv = silu_f(acc[mt][nb][r] + b);
                sH[row][col] = f2bf(mv);
                g += mv;
                if (r == 3 || srow[row + 1] != srow[row]) {
                    atomicAdd(&agg[(size_t)srow[row] * HID + col], g);
                    g = 0.f;
                }
            }
            acc[mt][nb] = (f32x4)0.f;
        }
    }
    __syncthreads();

    // ---- phase 3: c1 = silu(m @ cw1 + cb1), K = 128 ----
    #pragma unroll
    for (int ks = 0; ks < 4; ++ks) {
        bf16x8 af[4];
        #pragma unroll
        for (int mt = 0; mt < 4; ++mt)
            af[mt] = *(bf16x8*)&sH[mt * 16 + lm][ks * 32 + quad * 8];
        #pragma unroll
        for (int nb = 0; nb < 2; ++nb) {
            int col = wave * 32 + nb * 16 + lm;
            bf16x8 bf = *(const bf16x8*)&wtc1[(size_t)col * HID + ks * 32 + quad * 8];
            #pragma unroll
            for (int mt = 0; mt < 4; ++mt)
                acc[mt][nb] = __builtin_amdgcn_mfma_f32_16x16x32_bf16(af[mt], bf, acc[mt][nb], 0, 0, 0);
        }
    }
    __syncthreads();   // phase-3 reads done before c1 overwrite
    // epilogue 3: write silu(c1) bf16 -> sH
    #pragma unroll
    for (int nb = 0; nb < 2; ++nb) {
        int col = wave * 32 + nb * 16 + lm;
        float b = sC1[col];
        #pragma unroll
        for (int mt = 0; mt < 4; ++mt)
            #pragma unroll
            for (int r = 0; r < 4; ++r)
                sH[mt * 16 + quad * 4 + r][col] = f2bf(silu_f(acc[mt][nb][r] + b));
    }
    __syncthreads();

    // w = c1 . cw2 + cb2
    if (tid < 64) {
        float s = cb2[0];
        for (int k = 0; k < HID; k++) s += bf2f(((unsigned short*)sH[tid])[k]) * sV[k];
        sW[tid] = s;
    }
    __syncthreads();
    // coords update: per-run leader, 3 atomics per distinct row
    if (tid < 64) {
        bool leader = (tid == 0) || (srow[tid] != srow[tid - 1]);
        if (leader) {
            int rr = srow[tid];
            float ax = 0.f, ay = 0.f, az = 0.f;
            for (int k = tid; k < 64 && srow[k] == rr; ++k) {
                ax += sW[k] * sdiff[k][0];
                ay += sW[k] * sdiff[k][1];
                az += sW[k] * sdiff[k][2];
            }
            atomicAdd(&coords_next[3*rr+0], ax);
            atomicAdd(&coords_next[3*rr+1], ay);
            atomicAdd(&coords_next[3*rr+2], az);
        }
    }
}

// ---------------- node update (MFMA, col-split): feats' = silu([feats|agg] @ fw + fb) ----
// 32 rows/block (313 blocks), 4 waves, wave w owns cols [32w,32w+32), 2 m-tiles each.
__global__ __launch_bounds__(256) void node_kernel(
    const short* __restrict__ featsB, const float* __restrict__ agg,
    const short* __restrict__ wtf, const float* __restrict__ fb,
    short* __restrict__ outB)
{
    __shared__ short sA[32][72];
    __shared__ short sO[32][136];
    __shared__ float sFb[HID];

    const int tid = threadIdx.x;
    const int n0 = blockIdx.x * 32;
    const int wave = tid >> 6, lane = tid & 63, quad = lane >> 4, lm = lane & 15;

    if (tid < HID) sFb[tid] = fb[tid];

    f32x4 acc[2][2];
    acc[0][0] = (f32x4)0.f; acc[0][1] = (f32x4)0.f;
    acc[1][0] = (f32x4)0.f; acc[1][1] = (f32x4)0.f;
    __syncthreads();

    for (int c = 0; c < 4; ++c) {   // K = 256, 4 chunks of 64
        int k0 = c * 64;
        {   // stage 32 rows x 64 k: thread -> row tid>>3, 8 shorts at (tid&7)*8
            int el = tid >> 3, kq = (tid & 7) * 8;
            int node = n0 + el;
            if (node < N_NODES) {
                if (c < 2) {
                    *(bf16x8*)&sA[el][kq] =
                        *(const bf16x8*)&featsB[(size_t)node * HID + k0 + kq];
                } else {
                    const float* ap = &agg[(size_t)node * HID + (k0 - 128) + kq];
                    bf16x8 v;
                    #pragma unroll
                    for (int j = 0; j < 8; ++j) v[j] = f2bf(ap[j]);
                    *(bf16x8*)&sA[el][kq] = v;
                }
            } else {
                *(bf16x8*)&sA[el][kq] = (bf16x8)0;
            }
        }
        __syncthreads();
        #pragma unroll
        for (int h = 0; h < 2; ++h) {
            bf16x8 af[2];
            af[0] = *(bf16x8*)&sA[lm][h * 32 + quad * 8];
            af[1] = *(bf16x8*)&sA[16 + lm][h * 32 + quad * 8];
            #pragma unroll
            for (int nb = 0; nb < 2; ++nb) {
                int col = wave * 32 + nb * 16 + lm;
                bf16x8 bf = *(const bf16x8*)&wtf[(size_t)col * 256 + k0 + h * 32 + quad * 8];
                acc[0][nb] = __builtin_amdgcn_mfma_f32_16x16x32_bf16(af[0], bf, acc[0][nb], 0, 0, 0);
                acc[1][nb] = __builtin_amdgcn_mfma_f32_16x16x32_bf16(af[1], bf, acc[1][nb], 0, 0, 0);
            }
        }
        __syncthreads();
    }
    #pragma unroll
    for (int nb = 0; nb < 2; ++nb) {
        int col = wave * 32 + nb * 16 + lm;
        float b = sFb[col];
        #pragma unroll
        for (int mt = 0; mt < 2; ++mt)
            #pragma unroll
            for (int r = 0; r < 4; ++r)
                sO[mt * 16 + quad * 4 + r][col] = f2bf(silu_f(acc[mt][nb][r] + b));
    }
    __syncthreads();
    {   // cooperative coalesced bf16 write: thread -> row tid>>3, 8 shorts
        int row = tid >> 3, ch = (tid & 7) * 8;
        int hrow = row >> 1;      // 32 rows, 2 passes over 16B chunks
        (void)hrow;
        int node = n0 + row;
        if (node < N_NODES)
            *(bf16x8*)&outB[(size_t)node * HID + ch] = *(bf16x8*)&sO[row][ch];
        row += 0; // second half of the 128 cols
        if (node < N_NODES)
            *(bf16x8*)&outB[(size_t)node * HID + 64 + ch] = *(bf16x8*)&sO[row][64 + ch];
    }
}

// ---------------- energy head + global sum (fp32 VALU, reads bf16 feats) ----------------
#define FMA8(r, aq) \
    acc[r][0] += (aq)*b0.x; acc[r][1] += (aq)*b0.y; acc[r][2] += (aq)*b0.z; acc[r][3] += (aq)*b0.w; \
    acc[r][4] += (aq)*b1.x; acc[r][5] += (aq)*b1.y; acc[r][6] += (aq)*b1.z; acc[r][7] += (aq)*b1.w;

__global__ __launch_bounds__(256) void energy_kernel(
    const short* __restrict__ featsB,
    const float* __restrict__ ew1, const float* __restrict__ eb1,
    const float* __restrict__ ew2, const float* __restrict__ eb2,
    float* __restrict__ out)
{
    __shared__ float sA[64][20];
    __shared__ float sB[16][HID];
    __shared__ float sV[HID];
    __shared__ float red[256];
    int tid = threadIdx.x;
    int n0 = blockIdx.x * 64;
    const int tr = tid >> 4, tc = tid & 15;
    const int r0 = tr * 4, c0 = tc * 4, c1 = c0 + 64;
    const int el = tid >> 2, kq = (tid & 3) * 4;

    if (tid < HID) sV[tid] = ew2[tid];

    float acc[4][8];
    #pragma unroll
    for (int i = 0; i < 4; i++)
        #pragma unroll
        for (int j = 0; j < 8; j++) acc[i][j] = 0.f;

    for (int kt = 0; kt < 8; ++kt) {   // K = 128
        int k0 = kt * 16;
        {
            int k = k0 + kq;
            int node = n0 + el;
            float4 v = make_float4(0,0,0,0);
            if (node < N_NODES) {
                const unsigned short* p = (const unsigned short*)&featsB[(size_t)node * HID + k];
                v.x = bf2f(p[0]); v.y = bf2f(p[1]); v.z = bf2f(p[2]); v.w = bf2f(p[3]);
            }
            *(float4*)&sA[el][kq] = v;
        }
        {
            int bk = tid >> 4, bj = (tid & 15) * 8;
            int k = k0 + bk;
            *(float4*)&sB[bk][bj]     = *(const float4*)&ew1[(size_t)k * HID + bj];
            *(float4*)&sB[bk][bj + 4] = *(const float4*)&ew1[(size_t)k * HID + bj + 4];
        }
        __syncthreads();
        #pragma unroll
        for (int kk4 = 0; kk4 < 4; ++kk4) {
            float4 a0 = *(const float4*)&sA[r0 + 0][kk4 * 4];
            float4 a1 = *(const float4*)&sA[r0 + 1][kk4 * 4];
            float4 a2 = *(const float4*)&sA[r0 + 2][kk4 * 4];
            float4 a3 = *(const float4*)&sA[r0 + 3][kk4 * 4];
            #pragma unroll
            for (int q = 0; q < 4; ++q) {
                int kk = kk4 * 4 + q;
                float4 b0 = *(const float4*)&sB[kk][c0];
                float4 b1 = *(const float4*)&sB[kk][c1];
                float q0 = ((const float*)&a0)[q], q1 = ((const float*)&a1)[q];
                float q2 = ((const float*)&a2)[q], q3 = ((const float*)&a3)[q];
                FMA8(0, q0) FMA8(1, q1) FMA8(2, q2) FMA8(3, q3)
            }
        }
        __syncthreads();
    }
    float part = 0.f;
    #pragma unroll
    for (int i = 0; i < 4; i++) {
        int node = n0 + r0 + i;
        if (node < N_NODES) {
            #pragma unroll
            for (int j = 0; j < 4; j++) {
                part += silu_f(acc[i][j]     + eb1[c0+j]) * sV[c0+j];
                part += silu_f(acc[i][4 + j] + eb1[c1+j]) * sV[c1+j];
            }
        }
    }
    red[tid] = part;
    __syncthreads();
    for (int s = 128; s > 0; s >>= 1) {
        if (tid < s) red[tid] += red[tid + s];
        __syncthreads();
    }
    if (tid == 0) {
        float v = red[0];
        if (blockIdx.x == 0) v += eb2[0] * (float)N_NODES;
        atomicAdd(out, v);
    }
}

// ---------------- launcher ----------------

extern "C" void kernel_launch(void* const* d_in, const int* in_sizes, int n_in,
                              void* d_out, int out_size, void* d_ws, size_t ws_size,
                              hipStream_t stream)
{
    const int*   an     = (const int*)  d_in[0];
    const float* coords = (const float*)d_in[1];
    const int*   ei     = (const int*)  d_in[2];
    const float* embed  = (const float*)d_in[3];
    const float* mw1 = (const float*)d_in[4];
    const float* mb1 = (const float*)d_in[5];
    const float* mw2 = (const float*)d_in[6];
    const float* mb2 = (const float*)d_in[7];
    const float* cw1 = (const float*)d_in[8];
    const float* cb1 = (const float*)d_in[9];
    const float* cw2 = (const float*)d_in[10];
    const float* cb2 = (const float*)d_in[11];
    const float* fw  = (const float*)d_in[12];
    const float* fb  = (const float*)d_in[13];
    const float* ew1 = (const float*)d_in[14];
    const float* eb1 = (const float*)d_in[15];
    const float* ew2 = (const float*)d_in[16];
    const float* eb2 = (const float*)d_in[17];
    float* out = (float*)d_out;

    char* w = (char*)d_ws;
    size_t off = 0;
    auto alloc = [&](size_t bytes) -> char* {
        char* p = w + off;
        off = (off + bytes + 511) & ~(size_t)511;
        return p;
    };
    short* featsB0 = (short*)alloc((size_t)N_NODES * HID * 2);
    short* featsB1 = (short*)alloc((size_t)N_NODES * HID * 2);
    float* agg     = (float*)alloc((size_t)N_NODES * HID * 4);
    float* cA      = (float*)alloc((size_t)N_NODES * 3 * 4);
    float* cB      = (float*)alloc((size_t)N_NODES * 3 * 4);
    float* d0      = (float*)alloc((size_t)N_EDGES * 4);
    float* cut0    = (float*)alloc((size_t)N_EDGES * 4);
    int*   sorted  = (int*)  alloc((size_t)N_EDGES * 4);
    int*   cnt     = (int*)  alloc((size_t)N_NODES * 4);
    int*   cursor  = (int*)  alloc((size_t)N_NODES * 4);
    short* wtm1    = (short*)alloc((size_t)N_LAYERS * 40960 * 2);
    short* wtm2    = (short*)alloc((size_t)N_LAYERS * 16384 * 2);
    short* wtc1    = (short*)alloc((size_t)N_LAYERS * 16384 * 2);
    short* wtf     = (short*)alloc((size_t)N_LAYERS * 32768 * 2);

    const int* erow = ei;
    const int* ecol = ei + N_EDGES;

    hipMemsetAsync(cnt, 0, (size_t)N_NODES * 4, stream);
    init_feats_kernel<<<(N_NODES * HID + 255) / 256, 256, 0, stream>>>(an, embed, featsB0);
    wtrans_kernel<<<(N_LAYERS * WT_L + 255) / 256, 256, 0, stream>>>(
        mw1, mw2, cw1, fw, wtm1, wtm2, wtc1, wtf);
    hipMemcpyAsync(cA, coords, (size_t)N_NODES * 3 * 4, hipMemcpyDeviceToDevice, stream);
    hist_kernel<<<(N_EDGES + 255) / 256, 256, 0, stream>>>(erow, cnt);
    scan_kernel<<<1, 256, 0, stream>>>(cnt, cursor);
    scatter_kernel<<<(N_EDGES + 255) / 256, 256, 0, stream>>>(erow, cursor, sorted);
    edgegeom_kernel<<<N_EDGES / 256, 256, 0, stream>>>(sorted, erow, ecol, cA, d0, cut0);

    short* fc = featsB0; short* fn = featsB1;
    float* cc = cA;      float* cn = cB;
    for (int l = 0; l < N_LAYERS; ++l) {
        hipMemsetAsync(agg, 0, (size_t)N_NODES * HID * 4, stream);
        hipMemcpyAsync(cn, cc, (size_t)N_NODES * 3 * 4, hipMemcpyDeviceToDevice, stream);
        edge_kernel<<<N_EDGES / 64, 256, 0, stream>>>(
            sorted, erow, ecol, cc, cn, fc, d0, cut0,
            wtm1 + (size_t)l * 40960, mb1 + (size_t)l * HID,
            wtm2 + (size_t)l * 16384, mb2 + (size_t)l * HID,
            wtc1 + (size_t)l * 16384, cb1 + (size_t)l * HID,
            cw2 + (size_t)l * HID,    cb2 + l, agg);
        node_kernel<<<(N_NODES + 31) / 32, 256, 0, stream>>>(
            fc, agg, wtf + (size_t)l * 32768, fb + (size_t)l * HID, fn);
        { short* t = fc; fc = fn; fn = t; }
        { float* t = cc; cc = cn; cn = t; }
    }
    hipMemsetAsync(out, 0, 4, stream);
    energy_kernel<<<(N_NODES + 63) / 64, 256, 0, stream>>>(fc, ew1, eb1, ew2, eb2, out);
}